// Round 14
// baseline (149.698 us; speedup 1.0000x reference)
//
#include <hip/hip_runtime.h>
#include <math.h>

#define IMG 512

typedef __attribute__((ext_vector_type(4))) short short4_t;
typedef __attribute__((ext_vector_type(8))) short short8;
typedef __attribute__((ext_vector_type(4))) float f32x4;
typedef __attribute__((ext_vector_type(16))) float f32x16;
typedef __attribute__((ext_vector_type(2))) unsigned int u32x2;

__device__ __forceinline__ unsigned short f2bf(float f) {
  unsigned u = __builtin_bit_cast(unsigned, f);
  u += 0x7FFFu + ((u >> 16) & 1u);  // RNE
  return (unsigned short)(u >> 16);
}
// packed f32x2 -> bf16x2 (RNE), single VALU op
__device__ __forceinline__ unsigned cvtpk(float lo, float hi) {
  unsigned r;
  asm("v_cvt_pk_bf16_f32 %0, %1, %2" : "=v"(r) : "v"(lo), "v"(hi));
  return r;
}
__device__ __forceinline__ float bf2f(unsigned short v) {
  return __builtin_bit_cast(float, ((unsigned)v) << 16);
}

// ---------------------------------------------------------------------------
// k_prep: lane-major conv1 A-fragments (32x32x16, K padded 12->16 per kk=dy).
// ---------------------------------------------------------------------------
__global__ __launch_bounds__(256) void k_prep(const float* __restrict__ w1,
                                              unsigned short* __restrict__ w1f) {
  const int t = threadIdx.x;
  if (t < 192) {
    const int kk = t >> 6, lane = t & 63;
    const int oc = lane & 31, hi = lane >> 5;
#pragma unroll
    for (int j = 0; j < 8; ++j) {
      const int dxp = 2 * hi + (j >> 2), ic = j & 3;
      float v = (dxp < 3) ? w1[((oc * 4 + ic) * 3 + kk) * 3 + dxp] : 0.f;
      w1f[(kk * 64 + lane) * 8 + j] = f2bf(v);
    }
  }
}

// ---------------------------------------------------------------------------
// Pass 1: conv1 (bf16 MFMA 32x32x16) + ReLU + pool over exact 32x32 tiles.
// (Round-11 lesson: bigger tiles spilled accumulators; keep this form.)
// ---------------------------------------------------------------------------
__global__ __launch_bounds__(256, 3) void k_pool(
    const float* __restrict__ x, const unsigned short* __restrict__ w1f,
    const float* __restrict__ b1, float* __restrict__ red_out, int use_atomic) {
  __shared__ unsigned short xs[34 * 40 * 4];
  __shared__ float pools[4][2][16];
  const int bid = blockIdx.x;
  const int swz = (bid & 7) * 512 + (bid >> 3);  // XCD-contiguous
  const int bx = swz & 15, by = (swz >> 4) & 15, n = swz >> 8;
  const int x0 = bx * 32, y0 = by * 32;
  const int t = threadIdx.x, lane = t & 63, wv = t >> 6;
  const int hi = lane >> 5;

  short8 A1[3];
#pragma unroll
  for (int kk = 0; kk < 3; ++kk)
    A1[kk] = *(const short8*)&w1f[(kk * 64 + lane) * 8];
  float bias_r[16];
#pragma unroll
  for (int r = 0; r < 16; ++r) {
    float bl = b1[(r & 3) + 8 * (r >> 2)], bh = b1[(r & 3) + 8 * (r >> 2) + 4];
    bias_r[r] = hi ? bh : bl;
  }

  const int sx = x0 - 4;
  const long CS = (long)IMG * IMG;
  for (int i = t; i < 340; i += 256) {
    const int row = i / 10, cb = i % 10;
    const int gy = y0 - 1 + row, gx0 = sx + cb * 4;
    f32x4 v0 = {0.f, 0.f, 0.f, 0.f}, v1 = v0, v2 = v0, v3 = v0;
    if (gy >= 0 && gy < IMG && gx0 >= 0 && gx0 < IMG) {
      const float* p = x + (((long)(n * 4) * IMG + gy) * IMG + gx0);
      v0 = *(const f32x4*)p;
      v1 = *(const f32x4*)(p + CS);
      v2 = *(const f32x4*)(p + 2 * CS);
      v3 = *(const f32x4*)(p + 3 * CS);
    }
    unsigned short* d = &xs[(row * 40 + cb * 4) * 4];
#pragma unroll
    for (int j = 0; j < 4; ++j) {
      u32x2 w;
      w[0] = cvtpk(v0[j], v1[j]);
      w[1] = cvtpk(v2[j], v3[j]);
      *(u32x2*)(d + j * 4) = w;
    }
  }
  __syncthreads();

  float pacc[16];
#pragma unroll
  for (int r = 0; r < 16; ++r) pacc[r] = 0.f;
  const int cx0 = (lane & 31) + 2 * hi + 3;
  const unsigned short* pP = &xs[((wv * 8) * 40 + cx0) * 4];
#define LOADP(K)                                                              \
  __builtin_shufflevector(*(const short4_t*)(pP + (K)*160),                   \
                          *(const short4_t*)(pP + (K)*160 + 4), 0, 1, 2, 3,   \
                          4, 5, 6, 7)
  short8 Ba, Bb, Bc;
  Ba = LOADP(0);
  Bb = LOADP(1);
#define P_ITER(IT, B0, B1, B2)                                                \
  {                                                                           \
    B2 = LOADP((IT) + 2);                                                     \
    f32x16 C;                                                                 \
    _Pragma("unroll") for (int r = 0; r < 16; ++r) C[r] = bias_r[r];          \
    C = __builtin_amdgcn_mfma_f32_32x32x16_bf16(A1[0], B0, C, 0, 0, 0);       \
    C = __builtin_amdgcn_mfma_f32_32x32x16_bf16(A1[1], B1, C, 0, 0, 0);       \
    C = __builtin_amdgcn_mfma_f32_32x32x16_bf16(A1[2], B2, C, 0, 0, 0);       \
    _Pragma("unroll") for (int r = 0; r < 16; ++r)                            \
        pacc[r] += fmaxf(C[r], 0.f);                                          \
  }
  P_ITER(0, Ba, Bb, Bc)
  P_ITER(1, Bb, Bc, Ba)
  P_ITER(2, Bc, Ba, Bb)
  P_ITER(3, Ba, Bb, Bc)
  P_ITER(4, Bb, Bc, Ba)
  P_ITER(5, Bc, Ba, Bb)
  P_ITER(6, Ba, Bb, Bc)
  P_ITER(7, Bb, Bc, Ba)
#undef P_ITER
#undef LOADP
#pragma unroll
  for (int r = 0; r < 16; ++r) {
#pragma unroll
    for (int m = 1; m < 32; m <<= 1) pacc[r] += __shfl_xor(pacc[r], m);
  }
  if ((lane & 31) == 0) {
#pragma unroll
    for (int r = 0; r < 16; ++r) pools[wv][hi][r] = pacc[r];
  }
  __syncthreads();
  if (t < 32) {
    const int c = t;
    const int hic = (c >> 2) & 1, reg = (c & 3) + 4 * (c >> 3);
    float s = pools[0][hic][reg] + pools[1][hic][reg] + pools[2][hic][reg] +
              pools[3][hic][reg];
    if (use_atomic) {
      atomicAdd(&red_out[n * 32 + c], s);
    } else {
      red_out[(n * 256 + by * 16 + bx) * 32 + c] = s;
    }
  }
}

// ---------------------------------------------------------------------------
// Pass 2: reduce partials (det path) + SE head + emit conv2 A-fragments:
// w2f[((n*18+s)*64+lane)*8+j], s=(dyy*3+dx), lane:(row16=oc+4*yo, cg),
// value = (0<=dyy-yo<3) ? w2[oc][c=cg*8+j][dyy-yo][dx]*p[c] : 0
// ---------------------------------------------------------------------------
__global__ __launch_bounds__(256) void k_se(
    const float* __restrict__ partials, const float* __restrict__ sums,
    const float* __restrict__ w_se1, const float* __restrict__ b_se1,
    const float* __restrict__ w_se2, const float* __restrict__ b_se2,
    const float* __restrict__ w2, unsigned short* __restrict__ w2f, int det) {
  const int n = blockIdx.x, t = threadIdx.x;
  __shared__ float red[8][32];
  __shared__ float mean_s[32], f1[16], p[32];
  if (det) {
    const int c = t & 31, s = t >> 5;
    float a = 0.f;
    for (int i = s * 32; i < s * 32 + 32; ++i)
      a += partials[(n * 256 + i) * 32 + c];
    red[s][c] = a;
    __syncthreads();
    if (t < 32) {
      float v = 0.f;
#pragma unroll
      for (int s2 = 0; s2 < 8; ++s2) v += red[s2][t];
      mean_s[t] = v * (1.0f / (512.f * 512.f));
    }
  } else {
    if (t < 32) mean_s[t] = sums[n * 32 + t] * (1.0f / (512.f * 512.f));
  }
  __syncthreads();
  if (t < 16) {
    float a = b_se1[t];
#pragma unroll
    for (int c = 0; c < 32; ++c) a += w_se1[t * 32 + c] * mean_s[c];
    f1[t] = fmaxf(a, 0.f);
  }
  __syncthreads();
  if (t < 32) {
    float a = b_se2[t];
#pragma unroll
    for (int c = 0; c < 16; ++c) a += w_se2[t * 16 + c] * f1[c];
    p[t] = 1.f / (1.f + expf(-a));
  }
  __syncthreads();
  for (int i = t; i < 9216; i += 256) {
    const int s = i >> 9, rem = i & 511, lane2 = rem >> 3, j = rem & 7;
    const int oc = lane2 & 3, yo = (lane2 >> 2) & 3, cg = lane2 >> 4;
    const int c = cg * 8 + j;
    const int dyy = s / 3, dx = s - dyy * 3, dy = dyy - yo;
    float v = 0.f;
    if (dy >= 0 && dy < 3) v = w2[(oc * 32 + c) * 9 + dy * 3 + dx] * p[c];
    w2f[((n * 18 + s) * 64 + lane2) * 8 + j] = f2bf(v);
  }
}

// ---------------------------------------------------------------------------
// Pass 3: 2-PHASE hs split of round-8's structure. Tile 30 cols x 16 rows,
// but hs is only 10 rows (20.5 KB): phase P computes conv1 for h rows
// y0-1+8P..y0+8+8P then conv2+epilogue for out rows y0+8P..y0+8P+7.
// LDS 26.9 KB -> 4-5 blocks/CU (was 43.5 KB -> 3). Cost: 2 overlap conv1
// rows recomputed + 2 extra barriers. A2 reloaded per phase (L2-hot) and
// pinned only within the phase -> conv1 peak ~70 VGPR, conv2 ~105, cap 128
// (R9/R11 spill lesson). Same lane maps/swizzle/staging/epilogue as R13.
// ---------------------------------------------------------------------------
__global__ __launch_bounds__(256, 4) void k_main(
    const float* __restrict__ x, const unsigned short* __restrict__ w1f,
    const float* __restrict__ b1, const unsigned short* __restrict__ w2f,
    const float* __restrict__ b2, float* __restrict__ out) {
  __shared__ unsigned short xs[20 * 40 * 4];
  __shared__ unsigned short hs[10 * 32 * 32];
  const int bid = blockIdx.x;
  const int swz = (bid & 7) * 1152 + (bid >> 3);  // XCD-contiguous
  const int bx = swz % 18;
  const int q = swz / 18;
  const int by = q & 31, n = q >> 5;
  const int x0 = bx * 30, y0 = by * 16;
  const int t = threadIdx.x, lane = t & 63, wv = t >> 6;
  const int hi = lane >> 5;

  short8 A1[3];
#pragma unroll
  for (int kk = 0; kk < 3; ++kk)
    A1[kk] = *(const short8*)&w1f[(kk * 64 + lane) * 8];
  float bias_r[16];
#pragma unroll
  for (int r = 0; r < 16; ++r) {
    float bl = b1[(r & 3) + 8 * (r >> 2)], bh = b1[(r & 3) + 8 * (r >> 2) + 4];
    bias_r[r] = hi ? bh : bl;
  }

  const int sx = (x0 - 4) & ~3;
  const long CS = (long)IMG * IMG;
  for (int i = t; i < 200; i += 256) {
    const int row = i / 10, cb = i % 10;
    const int gy = y0 - 2 + row, gx0 = sx + cb * 4;
    f32x4 v0 = {0.f, 0.f, 0.f, 0.f}, v1 = v0, v2 = v0, v3 = v0;
    if (gy >= 0 && gy < IMG && gx0 >= 0 && gx0 < IMG) {
      const float* p = x + (((long)(n * 4) * IMG + gy) * IMG + gx0);
      v0 = *(const f32x4*)p;
      v1 = *(const f32x4*)(p + CS);
      v2 = *(const f32x4*)(p + 2 * CS);
      v3 = *(const f32x4*)(p + 3 * CS);
    }
    unsigned short* d = &xs[(row * 40 + cb * 4) * 4];
#pragma unroll
    for (int j = 0; j < 4; ++j) {
      u32x2 w;
      w[0] = cvtpk(v0[j], v1[j]);
      w[1] = cvtpk(v2[j], v3[j]);
      *(u32x2*)(d + j * 4) = w;
    }
  }
  __syncthreads();

  // ---- shared constants for both phases
  const int px = lane & 31;
  const int cx0 = px + 2 * hi + (x0 - 2 - sx);  // halo-aware delta
  const int q2 = (px >> 1) & 3;
  const int gxc = x0 - 1 + px;
  const bool colok = (gxc >= 0) && (gxc < IMG);
  const bool col_int = (x0 >= 1) && (x0 + 30 < IMG);  // block-uniform
  const int R0 = (wv < 2) ? 3 * wv : 6 + 2 * (wv - 2);  // rows 3,3,2,2

  const int px16 = lane & 15, cg = lane >> 4;
  const int grp = wv & 1, ybq = wv >> 1;  // px half, 4-row quad
  const int ox = grp * 16 + px16;
  const int yo = lane >> 4;
  const int gxo = x0 + ox;
  const bool epi_ok = (ox < 30) && (gxo < IMG);
  const float b20 = b2[0], b21 = b2[1], b22 = b2[2], b23 = b2[3];
  const int n4 = n * 4;
  int ph0 = ox, ph1 = ox + 1, ph2 = ox + 2;
  ph2 = ph2 < 31 ? ph2 : 31;
  ph1 = ph1 < 31 ? ph1 : 31;
  const int ba0 = ph0 * 64 + ((cg ^ ((ph0 >> 1) & 3)) << 4);
  const int ba1 = ph1 * 64 + ((cg ^ ((ph1 >> 1) & 3)) << 4);
  const int ba2 = ph2 * 64 + ((cg ^ ((ph2 >> 1) & 3)) << 4);
  const char* hb = (const char*)hs + (ybq * 4) * 2048;
  const int xcol = ox + (x0 - sx);
  const unsigned short* w2b = w2f + (size_t)n * 9216 + lane * 8;

#define LOADX(K)                                                              \
  __builtin_shufflevector(*(const short4_t*)(pR + (K)*160),                   \
                          *(const short4_t*)(pR + (K)*160 + 4), 0, 1, 2, 3,   \
                          4, 5, 6, 7)
#define C1_ITER(P, IT, B0, B1, B2)                                            \
  {                                                                           \
    B2 = LOADX((IT) + 2);                                                     \
    const int hy = R0 + (IT);                                                 \
    const int yi = y0 - 1 + (P)*8 + hy;                                       \
    const bool row_ok = (yi >= 0) && (yi < IMG);                              \
    f32x16 C;                                                                 \
    _Pragma("unroll") for (int r = 0; r < 16; ++r) C[r] = bias_r[r];          \
    C = __builtin_amdgcn_mfma_f32_32x32x16_bf16(A1[0], B0, C, 0, 0, 0);       \
    C = __builtin_amdgcn_mfma_f32_32x32x16_bf16(A1[1], B1, C, 0, 0, 0);       \
    C = __builtin_amdgcn_mfma_f32_32x32x16_bf16(A1[2], B2, C, 0, 0, 0);       \
    const int usb = hy * 1024 + px * 32 + (hi << 2);                          \
    if (row_ok && col_int) {                                                  \
      _Pragma("unroll") for (int g = 0; g < 4; ++g) {                         \
        u32x2 w;                                                              \
        w[0] = cvtpk(fmaxf(C[4 * g + 0], 0.f), fmaxf(C[4 * g + 1], 0.f));     \
        w[1] = cvtpk(fmaxf(C[4 * g + 2], 0.f), fmaxf(C[4 * g + 3], 0.f));     \
        *(u32x2*)&hs[usb + ((g ^ q2) << 3)] = w;                              \
      }                                                                       \
    } else if (row_ok) {                                                      \
      _Pragma("unroll") for (int g = 0; g < 4; ++g) {                         \
        unsigned p01 =                                                        \
            cvtpk(fmaxf(C[4 * g + 0], 0.f), fmaxf(C[4 * g + 1], 0.f));        \
        unsigned p23 =                                                        \
            cvtpk(fmaxf(C[4 * g + 2], 0.f), fmaxf(C[4 * g + 3], 0.f));        \
        u32x2 w;                                                              \
        w[0] = colok ? p01 : 0u;                                              \
        w[1] = colok ? p23 : 0u;                                              \
        *(u32x2*)&hs[usb + ((g ^ q2) << 3)] = w;                              \
      }                                                                       \
    } else {                                                                  \
      u32x2 z;                                                                \
      z[0] = 0u;                                                              \
      z[1] = 0u;                                                              \
      _Pragma("unroll") for (int g = 0; g < 4; ++g)                           \
          *(u32x2*)&hs[usb + ((g ^ q2) << 3)] = z;                            \
    }                                                                         \
  }
#define CONV1_PHASE(P)                                                        \
  {                                                                           \
    const unsigned short* pR = &xs[(((P)*8 + R0) * 40 + cx0) * 4];            \
    short8 Ba, Bb, Bc;                                                        \
    Ba = LOADX(0);                                                            \
    Bb = LOADX(1);                                                            \
    C1_ITER(P, 0, Ba, Bb, Bc)                                                 \
    C1_ITER(P, 1, Bb, Bc, Ba)                                                 \
    if (wv < 2) C1_ITER(P, 2, Bc, Ba, Bb)                                     \
  }

#define LOADF(R)                                                              \
  F0 = *(const short8*)(hb + (R)*2048 + ba0);                                 \
  F1 = *(const short8*)(hb + (R)*2048 + ba1);                                 \
  F2 = *(const short8*)(hb + (R)*2048 + ba2);
#define MFA(S0, S1, S2)                                                       \
  CA = __builtin_amdgcn_mfma_f32_16x16x32_bf16(A2_##S0, F0, CA, 0, 0, 0);     \
  CA = __builtin_amdgcn_mfma_f32_16x16x32_bf16(A2_##S1, F1, CA, 0, 0, 0);     \
  CA = __builtin_amdgcn_mfma_f32_16x16x32_bf16(A2_##S2, F2, CA, 0, 0, 0);
#define CONV2_PHASE(P)                                                        \
  {                                                                           \
    short8 A2_0 = *(const short8*)(w2b + 0 * 512);                            \
    short8 A2_1 = *(const short8*)(w2b + 1 * 512);                            \
    short8 A2_2 = *(const short8*)(w2b + 2 * 512);                            \
    short8 A2_3 = *(const short8*)(w2b + 3 * 512);                            \
    short8 A2_4 = *(const short8*)(w2b + 4 * 512);                            \
    short8 A2_5 = *(const short8*)(w2b + 5 * 512);                            \
    short8 A2_6 = *(const short8*)(w2b + 6 * 512);                            \
    short8 A2_7 = *(const short8*)(w2b + 7 * 512);                            \
    short8 A2_8 = *(const short8*)(w2b + 8 * 512);                            \
    short8 A2_9 = *(const short8*)(w2b + 9 * 512);                            \
    short8 A2_10 = *(const short8*)(w2b + 10 * 512);                          \
    short8 A2_11 = *(const short8*)(w2b + 11 * 512);                          \
    short8 A2_12 = *(const short8*)(w2b + 12 * 512);                          \
    short8 A2_13 = *(const short8*)(w2b + 13 * 512);                          \
    short8 A2_14 = *(const short8*)(w2b + 14 * 512);                          \
    short8 A2_15 = *(const short8*)(w2b + 15 * 512);                          \
    short8 A2_16 = *(const short8*)(w2b + 16 * 512);                          \
    short8 A2_17 = *(const short8*)(w2b + 17 * 512);                          \
    asm volatile("" ::"v"(A2_0), "v"(A2_1), "v"(A2_2), "v"(A2_3), "v"(A2_4),  \
                 "v"(A2_5), "v"(A2_6), "v"(A2_7), "v"(A2_8), "v"(A2_9),       \
                 "v"(A2_10), "v"(A2_11), "v"(A2_12), "v"(A2_13), "v"(A2_14),  \
                 "v"(A2_15), "v"(A2_16), "v"(A2_17));                         \
    __syncthreads();                                                          \
    f32x4 CA = {b20, b21, b22, b23};                                          \
    short8 F0, F1, F2;                                                        \
    __builtin_amdgcn_s_setprio(1);                                            \
    LOADF(0) MFA(0, 1, 2)                                                     \
    LOADF(1) MFA(3, 4, 5)                                                     \
    LOADF(2) MFA(6, 7, 8)                                                     \
    LOADF(3) MFA(9, 10, 11)                                                   \
    LOADF(4) MFA(12, 13, 14)                                                  \
    LOADF(5) MFA(15, 16, 17)                                                  \
    __builtin_amdgcn_s_setprio(0);                                            \
    if (epi_ok) {                                                             \
      const int gy = y0 + (P)*8 + ybq * 4 + yo;                               \
      const long i0 = ((long)n4 * IMG + gy) * IMG + gxo;                      \
      short4_t xv =                                                           \
          *(const short4_t*)&xs[(((P)*8 + ybq * 4 + yo + 2) * 40 + xcol) * 4];\
      out[i0] = fmaxf(CA[0], 0.f) * bf2f((unsigned short)xv[0]);              \
      out[i0 + CS] = fmaxf(CA[1], 0.f) * bf2f((unsigned short)xv[1]);         \
      out[i0 + 2 * CS] = fmaxf(CA[2], 0.f) * bf2f((unsigned short)xv[2]);     \
      out[i0 + 3 * CS] = fmaxf(CA[3], 0.f) * bf2f((unsigned short)xv[3]);     \
    }                                                                         \
  }

  // ---- phase 0: h rows y0-1..y0+8, out rows y0..y0+7
  CONV1_PHASE(0)
  CONV2_PHASE(0)
  __syncthreads();  // WAR: phase-1 conv1 overwrites hs after phase-0 reads
  // ---- phase 1: h rows y0+7..y0+16, out rows y0+8..y0+15
  CONV1_PHASE(1)
  CONV2_PHASE(1)

#undef CONV2_PHASE
#undef MFA
#undef LOADF
#undef CONV1_PHASE
#undef C1_ITER
#undef LOADX
}

// ---------------------------------------------------------------------------
extern "C" void kernel_launch(void* const* d_in, const int* in_sizes, int n_in,
                              void* d_out, int out_size, void* d_ws,
                              size_t ws_size, hipStream_t stream) {
  const float* x = (const float*)d_in[0];
  const float* w1 = (const float*)d_in[1];
  const float* b1 = (const float*)d_in[2];
  const float* w2 = (const float*)d_in[3];
  const float* b2 = (const float*)d_in[4];
  const float* w_se1 = (const float*)d_in[5];
  const float* b_se1 = (const float*)d_in[6];
  const float* w_se2 = (const float*)d_in[7];
  const float* b_se2 = (const float*)d_in[8];
  float* out = (float*)d_out;
  float* ws = (float*)d_ws;

  // ws: sums[512]f | w1f[1536]bf16 | w2f[147456]bf16 | partials[131072]f
  float* sums = ws;
  unsigned short* w1f = (unsigned short*)(ws + 512);
  unsigned short* w2f = w1f + 1536;
  float* partials = (float*)(w2f + 147456);
  const size_t need_full =
      512 * 4 + 1536 * 2 + (size_t)147456 * 2 + (size_t)131072 * 4;

  k_prep<<<1, 256, 0, stream>>>(w1, w1f);
  if (ws_size >= need_full) {
    k_pool<<<4096, 256, 0, stream>>>(x, w1f, b1, partials, 0);
    k_se<<<16, 256, 0, stream>>>(partials, sums, w_se1, b_se1, w_se2, b_se2,
                                 w2, w2f, 1);
  } else {
    hipMemsetAsync(sums, 0, 512 * sizeof(float), stream);
    k_pool<<<4096, 256, 0, stream>>>(x, w1f, b1, sums, 1);
    k_se<<<16, 256, 0, stream>>>(partials, sums, w_se1, b_se1, w_se2, b_se2,
                                 w2, w2f, 0);
  }
  k_main<<<9216, 256, 0, stream>>>(x, w1f, b1, w2f, b2, out);
}

// Round 15
// 99.700 us; speedup vs baseline: 1.5015x; 1.5015x over previous
//
#include <hip/hip_runtime.h>
#include <math.h>

#define IMG 512

typedef __attribute__((ext_vector_type(4))) short short4_t;
typedef __attribute__((ext_vector_type(8))) short short8;
typedef __attribute__((ext_vector_type(4))) float f32x4;
typedef __attribute__((ext_vector_type(16))) float f32x16;
typedef __attribute__((ext_vector_type(2))) unsigned int u32x2;

__device__ __forceinline__ unsigned short f2bf(float f) {
  unsigned u = __builtin_bit_cast(unsigned, f);
  u += 0x7FFFu + ((u >> 16) & 1u);  // RNE
  return (unsigned short)(u >> 16);
}
// packed f32x2 -> bf16x2 (RNE), single VALU op
__device__ __forceinline__ unsigned cvtpk(float lo, float hi) {
  unsigned r;
  asm("v_cvt_pk_bf16_f32 %0, %1, %2" : "=v"(r) : "v"(lo), "v"(hi));
  return r;
}
__device__ __forceinline__ float bf2f(unsigned short v) {
  return __builtin_bit_cast(float, ((unsigned)v) << 16);
}

// ---------------------------------------------------------------------------
// k_prep: lane-major conv1 A-fragments (32x32x16, K padded 12->16 per kk=dy).
// ---------------------------------------------------------------------------
__global__ __launch_bounds__(256) void k_prep(const float* __restrict__ w1,
                                              unsigned short* __restrict__ w1f) {
  const int t = threadIdx.x;
  if (t < 192) {
    const int kk = t >> 6, lane = t & 63;
    const int oc = lane & 31, hi = lane >> 5;
#pragma unroll
    for (int j = 0; j < 8; ++j) {
      const int dxp = 2 * hi + (j >> 2), ic = j & 3;
      float v = (dxp < 3) ? w1[((oc * 4 + ic) * 3 + kk) * 3 + dxp] : 0.f;
      w1f[(kk * 64 + lane) * 8 + j] = f2bf(v);
    }
  }
}

// ---------------------------------------------------------------------------
// Pass 1: conv1 (bf16 MFMA 32x32x16) + ReLU + pool over exact 32x32 tiles.
// (R11 lesson: bigger tiles spill accumulators to scratch; keep this form.)
// ---------------------------------------------------------------------------
__global__ __launch_bounds__(256, 3) void k_pool(
    const float* __restrict__ x, const unsigned short* __restrict__ w1f,
    const float* __restrict__ b1, float* __restrict__ red_out, int use_atomic) {
  __shared__ unsigned short xs[34 * 40 * 4];
  __shared__ float pools[4][2][16];
  const int bid = blockIdx.x;
  const int swz = (bid & 7) * 512 + (bid >> 3);  // XCD-contiguous
  const int bx = swz & 15, by = (swz >> 4) & 15, n = swz >> 8;
  const int x0 = bx * 32, y0 = by * 32;
  const int t = threadIdx.x, lane = t & 63, wv = t >> 6;
  const int hi = lane >> 5;

  short8 A1[3];
#pragma unroll
  for (int kk = 0; kk < 3; ++kk)
    A1[kk] = *(const short8*)&w1f[(kk * 64 + lane) * 8];
  float bias_r[16];
#pragma unroll
  for (int r = 0; r < 16; ++r) {
    float bl = b1[(r & 3) + 8 * (r >> 2)], bh = b1[(r & 3) + 8 * (r >> 2) + 4];
    bias_r[r] = hi ? bh : bl;
  }

  const int sx = x0 - 4;
  const long CS = (long)IMG * IMG;
  for (int i = t; i < 340; i += 256) {
    const int row = i / 10, cb = i % 10;
    const int gy = y0 - 1 + row, gx0 = sx + cb * 4;
    f32x4 v0 = {0.f, 0.f, 0.f, 0.f}, v1 = v0, v2 = v0, v3 = v0;
    if (gy >= 0 && gy < IMG && gx0 >= 0 && gx0 < IMG) {
      const float* p = x + (((long)(n * 4) * IMG + gy) * IMG + gx0);
      v0 = *(const f32x4*)p;
      v1 = *(const f32x4*)(p + CS);
      v2 = *(const f32x4*)(p + 2 * CS);
      v3 = *(const f32x4*)(p + 3 * CS);
    }
    unsigned short* d = &xs[(row * 40 + cb * 4) * 4];
#pragma unroll
    for (int j = 0; j < 4; ++j) {
      u32x2 w;
      w[0] = cvtpk(v0[j], v1[j]);
      w[1] = cvtpk(v2[j], v3[j]);
      *(u32x2*)(d + j * 4) = w;
    }
  }
  __syncthreads();

  float pacc[16];
#pragma unroll
  for (int r = 0; r < 16; ++r) pacc[r] = 0.f;
  const int cx0 = (lane & 31) + 2 * hi + 3;
  const unsigned short* pP = &xs[((wv * 8) * 40 + cx0) * 4];
#define LOADP(K)                                                              \
  __builtin_shufflevector(*(const short4_t*)(pP + (K)*160),                   \
                          *(const short4_t*)(pP + (K)*160 + 4), 0, 1, 2, 3,   \
                          4, 5, 6, 7)
  short8 Ba, Bb, Bc;
  Ba = LOADP(0);
  Bb = LOADP(1);
#define P_ITER(IT, B0, B1, B2)                                                \
  {                                                                           \
    B2 = LOADP((IT) + 2);                                                     \
    f32x16 C;                                                                 \
    _Pragma("unroll") for (int r = 0; r < 16; ++r) C[r] = bias_r[r];          \
    C = __builtin_amdgcn_mfma_f32_32x32x16_bf16(A1[0], B0, C, 0, 0, 0);       \
    C = __builtin_amdgcn_mfma_f32_32x32x16_bf16(A1[1], B1, C, 0, 0, 0);       \
    C = __builtin_amdgcn_mfma_f32_32x32x16_bf16(A1[2], B2, C, 0, 0, 0);       \
    _Pragma("unroll") for (int r = 0; r < 16; ++r)                            \
        pacc[r] += fmaxf(C[r], 0.f);                                          \
  }
  P_ITER(0, Ba, Bb, Bc)
  P_ITER(1, Bb, Bc, Ba)
  P_ITER(2, Bc, Ba, Bb)
  P_ITER(3, Ba, Bb, Bc)
  P_ITER(4, Bb, Bc, Ba)
  P_ITER(5, Bc, Ba, Bb)
  P_ITER(6, Ba, Bb, Bc)
  P_ITER(7, Bb, Bc, Ba)
#undef P_ITER
#undef LOADP
#pragma unroll
  for (int r = 0; r < 16; ++r) {
#pragma unroll
    for (int m = 1; m < 32; m <<= 1) pacc[r] += __shfl_xor(pacc[r], m);
  }
  if ((lane & 31) == 0) {
#pragma unroll
    for (int r = 0; r < 16; ++r) pools[wv][hi][r] = pacc[r];
  }
  __syncthreads();
  if (t < 32) {
    const int c = t;
    const int hic = (c >> 2) & 1, reg = (c & 3) + 4 * (c >> 3);
    float s = pools[0][hic][reg] + pools[1][hic][reg] + pools[2][hic][reg] +
              pools[3][hic][reg];
    if (use_atomic) {
      atomicAdd(&red_out[n * 32 + c], s);
    } else {
      red_out[(n * 256 + by * 16 + bx) * 32 + c] = s;
    }
  }
}

// ---------------------------------------------------------------------------
// Pass 2: reduce partials (det path) + SE head + emit conv2 A-fragments:
// w2f[((n*18+s)*64+lane)*8+j], s=(dyy*3+dx), lane:(row16=oc+4*yo, cg),
// value = (0<=dyy-yo<3) ? w2[oc][c=cg*8+j][dyy-yo][dx]*p[c] : 0
// ---------------------------------------------------------------------------
__global__ __launch_bounds__(256) void k_se(
    const float* __restrict__ partials, const float* __restrict__ sums,
    const float* __restrict__ w_se1, const float* __restrict__ b_se1,
    const float* __restrict__ w_se2, const float* __restrict__ b_se2,
    const float* __restrict__ w2, unsigned short* __restrict__ w2f, int det) {
  const int n = blockIdx.x, t = threadIdx.x;
  __shared__ float red[8][32];
  __shared__ float mean_s[32], f1[16], p[32];
  if (det) {
    const int c = t & 31, s = t >> 5;
    float a = 0.f;
    for (int i = s * 32; i < s * 32 + 32; ++i)
      a += partials[(n * 256 + i) * 32 + c];
    red[s][c] = a;
    __syncthreads();
    if (t < 32) {
      float v = 0.f;
#pragma unroll
      for (int s2 = 0; s2 < 8; ++s2) v += red[s2][t];
      mean_s[t] = v * (1.0f / (512.f * 512.f));
    }
  } else {
    if (t < 32) mean_s[t] = sums[n * 32 + t] * (1.0f / (512.f * 512.f));
  }
  __syncthreads();
  if (t < 16) {
    float a = b_se1[t];
#pragma unroll
    for (int c = 0; c < 32; ++c) a += w_se1[t * 32 + c] * mean_s[c];
    f1[t] = fmaxf(a, 0.f);
  }
  __syncthreads();
  if (t < 32) {
    float a = b_se2[t];
#pragma unroll
    for (int c = 0; c < 16; ++c) a += w_se2[t * 16 + c] * f1[c];
    p[t] = 1.f / (1.f + expf(-a));
  }
  __syncthreads();
  for (int i = t; i < 9216; i += 256) {
    const int s = i >> 9, rem = i & 511, lane2 = rem >> 3, j = rem & 7;
    const int oc = lane2 & 3, yo = (lane2 >> 2) & 3, cg = lane2 >> 4;
    const int c = cg * 8 + j;
    const int dyy = s / 3, dx = s - dyy * 3, dy = dyy - yo;
    float v = 0.f;
    if (dy >= 0 && dy < 3) v = w2[(oc * 32 + c) * 9 + dy * 3 + dx] * p[c];
    w2f[((n * 18 + s) * 64 + lane2) * 8 + j] = f2bf(v);
  }
}

// ---------------------------------------------------------------------------
// Pass 3 (R13, best measured: 64 us): fused conv1(32x32x16) -> hs(LDS) ->
// conv2(16x16x32 full-M K=576) + residual multiply. Tile 30 cols x 16 rows.
// hs [18][32 px][32 c] bf16, swizzle q2=(px>>1)&3 on 16B blocks. conv2:
// 10 row-levels, frags shared by chains A/B at levels 4-5; setprio(1)
// around MFMA cluster; A2 pinned pre-barrier (VGPR 68, no spill).
// Epilogue residual x read from xs (bf16, 1 ds_read_b64 for all 4 ch).
// LDS 43.3 KB is minimal for this tile (xs 20 rows, hs 18x32 both tight);
// 3 blocks/CU. R9/R10/R11/R14 all showed occupancy/persistence transforms
// lose to spill or per-output overhead — this is the empirical optimum.
// ---------------------------------------------------------------------------
__global__ __launch_bounds__(256, 3) void k_main(
    const float* __restrict__ x, const unsigned short* __restrict__ w1f,
    const float* __restrict__ b1, const unsigned short* __restrict__ w2f,
    const float* __restrict__ b2, float* __restrict__ out) {
  __shared__ unsigned short xs[20 * 40 * 4];
  __shared__ unsigned short hs[18 * 32 * 32];
  const int bid = blockIdx.x;
  const int swz = (bid & 7) * 1152 + (bid >> 3);  // XCD-contiguous
  const int bx = swz % 18;
  const int q = swz / 18;
  const int by = q & 31, n = q >> 5;
  const int x0 = bx * 30, y0 = by * 16;
  const int t = threadIdx.x, lane = t & 63, wv = t >> 6;
  const int hi = lane >> 5;

  short8 A1[3];
#pragma unroll
  for (int kk = 0; kk < 3; ++kk)
    A1[kk] = *(const short8*)&w1f[(kk * 64 + lane) * 8];
  float bias_r[16];
#pragma unroll
  for (int r = 0; r < 16; ++r) {
    float bl = b1[(r & 3) + 8 * (r >> 2)], bh = b1[(r & 3) + 8 * (r >> 2) + 4];
    bias_r[r] = hi ? bh : bl;
  }

  const int sx = (x0 - 4) & ~3;
  const long CS = (long)IMG * IMG;
  for (int i = t; i < 200; i += 256) {
    const int row = i / 10, cb = i % 10;
    const int gy = y0 - 2 + row, gx0 = sx + cb * 4;
    f32x4 v0 = {0.f, 0.f, 0.f, 0.f}, v1 = v0, v2 = v0, v3 = v0;
    if (gy >= 0 && gy < IMG && gx0 >= 0 && gx0 < IMG) {
      const float* p = x + (((long)(n * 4) * IMG + gy) * IMG + gx0);
      v0 = *(const f32x4*)p;
      v1 = *(const f32x4*)(p + CS);
      v2 = *(const f32x4*)(p + 2 * CS);
      v3 = *(const f32x4*)(p + 3 * CS);
    }
    unsigned short* d = &xs[(row * 40 + cb * 4) * 4];
#pragma unroll
    for (int j = 0; j < 4; ++j) {
      u32x2 w;
      w[0] = cvtpk(v0[j], v1[j]);
      w[1] = cvtpk(v2[j], v3[j]);
      *(u32x2*)(d + j * 4) = w;
    }
  }
  __syncthreads();

  // ---- conv1 -> hs (hs = 0 outside image: conv2 zero-pads ITS input)
  {
    const int px = lane & 31;
    const int cx0 = px + 2 * hi + (x0 - 2 - sx);  // halo-aware delta
    const int q2 = (px >> 1) & 3;
    const int gxc = x0 - 1 + px;
    const bool colok = (gxc >= 0) && (gxc < IMG);
    const bool col_int = (x0 >= 1) && (x0 + 30 < IMG);  // block-uniform
    const int R0 = (wv < 2) ? wv * 5 : 10 + (wv - 2) * 4;  // rows 5,5,4,4
    const unsigned short* pR = &xs[(R0 * 40 + cx0) * 4];
#define LOADX(K)                                                              \
  __builtin_shufflevector(*(const short4_t*)(pR + (K)*160),                   \
                          *(const short4_t*)(pR + (K)*160 + 4), 0, 1, 2, 3,   \
                          4, 5, 6, 7)
    short8 Ba, Bb, Bc;
    Ba = LOADX(0);
    Bb = LOADX(1);
#define C1_ITER(IT, B0, B1, B2)                                               \
  {                                                                           \
    B2 = LOADX((IT) + 2);                                                     \
    const int hy = R0 + (IT);                                                 \
    const int yi = y0 - 1 + hy;                                               \
    const bool row_ok = (yi >= 0) && (yi < IMG);                              \
    f32x16 C;                                                                 \
    _Pragma("unroll") for (int r = 0; r < 16; ++r) C[r] = bias_r[r];          \
    C = __builtin_amdgcn_mfma_f32_32x32x16_bf16(A1[0], B0, C, 0, 0, 0);       \
    C = __builtin_amdgcn_mfma_f32_32x32x16_bf16(A1[1], B1, C, 0, 0, 0);       \
    C = __builtin_amdgcn_mfma_f32_32x32x16_bf16(A1[2], B2, C, 0, 0, 0);       \
    const int usb = hy * 1024 + px * 32 + (hi << 2);                          \
    if (row_ok && col_int) {                                                  \
      _Pragma("unroll") for (int g = 0; g < 4; ++g) {                         \
        u32x2 w;                                                              \
        w[0] = cvtpk(fmaxf(C[4 * g + 0], 0.f), fmaxf(C[4 * g + 1], 0.f));     \
        w[1] = cvtpk(fmaxf(C[4 * g + 2], 0.f), fmaxf(C[4 * g + 3], 0.f));     \
        *(u32x2*)&hs[usb + ((g ^ q2) << 3)] = w;                              \
      }                                                                       \
    } else if (row_ok) {                                                      \
      _Pragma("unroll") for (int g = 0; g < 4; ++g) {                         \
        unsigned p01 =                                                        \
            cvtpk(fmaxf(C[4 * g + 0], 0.f), fmaxf(C[4 * g + 1], 0.f));        \
        unsigned p23 =                                                        \
            cvtpk(fmaxf(C[4 * g + 2], 0.f), fmaxf(C[4 * g + 3], 0.f));        \
        u32x2 w;                                                              \
        w[0] = colok ? p01 : 0u;                                              \
        w[1] = colok ? p23 : 0u;                                              \
        *(u32x2*)&hs[usb + ((g ^ q2) << 3)] = w;                              \
      }                                                                       \
    } else {                                                                  \
      u32x2 z;                                                                \
      z[0] = 0u;                                                              \
      z[1] = 0u;                                                              \
      _Pragma("unroll") for (int g = 0; g < 4; ++g)                           \
          *(u32x2*)&hs[usb + ((g ^ q2) << 3)] = z;                            \
    }                                                                         \
  }
    C1_ITER(0, Ba, Bb, Bc)
    C1_ITER(1, Bb, Bc, Ba)
    C1_ITER(2, Bc, Ba, Bb)
    C1_ITER(3, Ba, Bb, Bc)
    if (wv < 2) C1_ITER(4, Bb, Bc, Ba)
#undef C1_ITER
#undef LOADX
  }

  // ---- conv2 A-frags: issue BEFORE barrier (overlap), pin in registers
  const unsigned short* w2b = w2f + (size_t)n * 9216 + lane * 8;
  short8 A2_0 = *(const short8*)(w2b + 0 * 512);
  short8 A2_1 = *(const short8*)(w2b + 1 * 512);
  short8 A2_2 = *(const short8*)(w2b + 2 * 512);
  short8 A2_3 = *(const short8*)(w2b + 3 * 512);
  short8 A2_4 = *(const short8*)(w2b + 4 * 512);
  short8 A2_5 = *(const short8*)(w2b + 5 * 512);
  short8 A2_6 = *(const short8*)(w2b + 6 * 512);
  short8 A2_7 = *(const short8*)(w2b + 7 * 512);
  short8 A2_8 = *(const short8*)(w2b + 8 * 512);
  short8 A2_9 = *(const short8*)(w2b + 9 * 512);
  short8 A2_10 = *(const short8*)(w2b + 10 * 512);
  short8 A2_11 = *(const short8*)(w2b + 11 * 512);
  short8 A2_12 = *(const short8*)(w2b + 12 * 512);
  short8 A2_13 = *(const short8*)(w2b + 13 * 512);
  short8 A2_14 = *(const short8*)(w2b + 14 * 512);
  short8 A2_15 = *(const short8*)(w2b + 15 * 512);
  short8 A2_16 = *(const short8*)(w2b + 16 * 512);
  short8 A2_17 = *(const short8*)(w2b + 17 * 512);
  asm volatile("" ::"v"(A2_0), "v"(A2_1), "v"(A2_2), "v"(A2_3), "v"(A2_4),
               "v"(A2_5), "v"(A2_6), "v"(A2_7), "v"(A2_8), "v"(A2_9),
               "v"(A2_10), "v"(A2_11), "v"(A2_12), "v"(A2_13), "v"(A2_14),
               "v"(A2_15), "v"(A2_16), "v"(A2_17));
  __syncthreads();

  // ---- conv2: 10 row-levels, frags shared by both chains at levels 4-5
  {
    const int px16 = lane & 15, cg = lane >> 4;
    const int grp = wv & 1, ybq = wv >> 1;
    const int ox = grp * 16 + px16;
    const int yo = lane >> 4;
    const int gxo = x0 + ox;
    const bool epi_ok = (ox < 30) && (gxo < IMG);
    const float b20 = b2[0], b21 = b2[1], b22 = b2[2], b23 = b2[3];
    const int n4 = n * 4;
    int ph0 = ox, ph1 = ox + 1, ph2 = ox + 2;
    ph2 = ph2 < 31 ? ph2 : 31;
    ph1 = ph1 < 31 ? ph1 : 31;
    const int ba0 = ph0 * 64 + ((cg ^ ((ph0 >> 1) & 3)) << 4);
    const int ba1 = ph1 * 64 + ((cg ^ ((ph1 >> 1) & 3)) << 4);
    const int ba2 = ph2 * 64 + ((cg ^ ((ph2 >> 1) & 3)) << 4);
    const char* hb = (const char*)hs + (ybq * 8) * 2048;
    f32x4 CA = {b20, b21, b22, b23};  // bias pre-folded into accumulator
    f32x4 CB = {b20, b21, b22, b23};
    short8 F0, F1, F2;

#define LOADF(R)                                                              \
  F0 = *(const short8*)(hb + (R)*2048 + ba0);                                 \
  F1 = *(const short8*)(hb + (R)*2048 + ba1);                                 \
  F2 = *(const short8*)(hb + (R)*2048 + ba2);
#define MFA(S0, S1, S2)                                                       \
  CA = __builtin_amdgcn_mfma_f32_16x16x32_bf16(A2_##S0, F0, CA, 0, 0, 0);     \
  CA = __builtin_amdgcn_mfma_f32_16x16x32_bf16(A2_##S1, F1, CA, 0, 0, 0);     \
  CA = __builtin_amdgcn_mfma_f32_16x16x32_bf16(A2_##S2, F2, CA, 0, 0, 0);
#define MFB(S0, S1, S2)                                                       \
  CB = __builtin_amdgcn_mfma_f32_16x16x32_bf16(A2_##S0, F0, CB, 0, 0, 0);     \
  CB = __builtin_amdgcn_mfma_f32_16x16x32_bf16(A2_##S1, F1, CB, 0, 0, 0);     \
  CB = __builtin_amdgcn_mfma_f32_16x16x32_bf16(A2_##S2, F2, CB, 0, 0, 0);

    __builtin_amdgcn_s_setprio(1);
    LOADF(0) MFA(0, 1, 2)
    LOADF(1) MFA(3, 4, 5)
    LOADF(2) MFA(6, 7, 8)
    LOADF(3) MFA(9, 10, 11)
    LOADF(4) MFA(12, 13, 14) MFB(0, 1, 2)
    LOADF(5) MFA(15, 16, 17) MFB(3, 4, 5)
    LOADF(6) MFB(6, 7, 8)
    LOADF(7) MFB(9, 10, 11)
    LOADF(8) MFB(12, 13, 14)
    LOADF(9) MFB(15, 16, 17)
    __builtin_amdgcn_s_setprio(0);
#undef LOADF
#undef MFA
#undef MFB

    // residual x from xs (bf16): one b64 per row covers all 4 channels
    const int xcol = ox + (x0 - sx);

#define EPI2(CV, YB)                                                          \
  if (epi_ok) {                                                               \
    const int gy = y0 + (YB) + yo;                                            \
    const long i0 = ((long)n4 * IMG + gy) * IMG + gxo;                        \
    short4_t xv = *(const short4_t*)&xs[(((YB) + yo + 2) * 40 + xcol) * 4];   \
    out[i0] = fmaxf(CV[0], 0.f) * bf2f((unsigned short)xv[0]);                \
    out[i0 + CS] = fmaxf(CV[1], 0.f) * bf2f((unsigned short)xv[1]);           \
    out[i0 + 2 * CS] = fmaxf(CV[2], 0.f) * bf2f((unsigned short)xv[2]);       \
    out[i0 + 3 * CS] = fmaxf(CV[3], 0.f) * bf2f((unsigned short)xv[3]);       \
  }
    EPI2(CA, ybq * 8)
    EPI2(CB, ybq * 8 + 4)
#undef EPI2
  }
}

// ---------------------------------------------------------------------------
extern "C" void kernel_launch(void* const* d_in, const int* in_sizes, int n_in,
                              void* d_out, int out_size, void* d_ws,
                              size_t ws_size, hipStream_t stream) {
  const float* x = (const float*)d_in[0];
  const float* w1 = (const float*)d_in[1];
  const float* b1 = (const float*)d_in[2];
  const float* w2 = (const float*)d_in[3];
  const float* b2 = (const float*)d_in[4];
  const float* w_se1 = (const float*)d_in[5];
  const float* b_se1 = (const float*)d_in[6];
  const float* w_se2 = (const float*)d_in[7];
  const float* b_se2 = (const float*)d_in[8];
  float* out = (float*)d_out;
  float* ws = (float*)d_ws;

  // ws: sums[512]f | w1f[1536]bf16 | w2f[147456]bf16 | partials[131072]f
  float* sums = ws;
  unsigned short* w1f = (unsigned short*)(ws + 512);
  unsigned short* w2f = w1f + 1536;
  float* partials = (float*)(w2f + 147456);
  const size_t need_full =
      512 * 4 + 1536 * 2 + (size_t)147456 * 2 + (size_t)131072 * 4;

  k_prep<<<1, 256, 0, stream>>>(w1, w1f);
  if (ws_size >= need_full) {
    k_pool<<<4096, 256, 0, stream>>>(x, w1f, b1, partials, 0);
    k_se<<<16, 256, 0, stream>>>(partials, sums, w_se1, b_se1, w_se2, b_se2,
                                 w2, w2f, 1);
  } else {
    hipMemsetAsync(sums, 0, 512 * sizeof(float), stream);
    k_pool<<<4096, 256, 0, stream>>>(x, w1f, b1, sums, 1);
    k_se<<<16, 256, 0, stream>>>(partials, sums, w_se1, b_se1, w_se2, b_se2,
                                 w2, w2f, 0);
  }
  k_main<<<9216, 256, 0, stream>>>(x, w1f, b1, w2f, b2, out);
}